// Round 2
// baseline (2439.537 us; speedup 1.0000x reference)
//
#include <hip/hip_runtime.h>
#include <math.h>

typedef unsigned short u16;
typedef unsigned int   u32;

#define NN   200000
#define EE   6400000
#define MPAD 200064            // 1563 * 128
#define SCAN_T 2048
#define CHUNK 98               // ceil(NN / SCAN_T)

typedef __attribute__((ext_vector_type(8))) __bf16 bf16x8;
typedef __attribute__((ext_vector_type(4))) float  f32x4;

// ---------- helpers ----------
__device__ __forceinline__ float bl(u32 u) { return __uint_as_float(u << 16); }
__device__ __forceinline__ float bh(u32 u) { return __uint_as_float(u & 0xffff0000u); }
__device__ __forceinline__ u16 f2b(float f) {          // f32 -> bf16 RTNE
    u32 u = __float_as_uint(f);
    u32 r = (u + 0x7fffu + ((u >> 16) & 1u)) >> 16;
    return (u16)r;
}

// ---------- init ----------
__global__ void zero_kernel(int* cnt, float* g, int n) {
    int i = blockIdx.x * 256 + threadIdx.x;
    if (i < n) cnt[i] = 0;
    if (i < 128) g[i] = 0.f;
}

// x (N,300) f32 -> xbf (MPAD,320) bf16, zero-padded rows/cols
__global__ void convert_x(const float* __restrict__ x, u16* __restrict__ xbf) {
    int id  = blockIdx.x * 256 + threadIdx.x;   // one float4 chunk (4 cols)
    int row = id / 80;                          // 80 chunks of 4 = 320 cols
    int c4  = id - row * 80;
    int c   = c4 * 4;
    u32 lo = 0, hi = 0;
    if (row < NN && c < 300) {                  // c <= 296 -> c+3 <= 299, in range
        float4 v = *(const float4*)(x + (size_t)row * 300 + c);
        lo = (u32)f2b(v.x) | ((u32)f2b(v.y) << 16);
        hi = (u32)f2b(v.z) | ((u32)f2b(v.w) << 16);
    }
    *(uint2*)(xbf + (size_t)row * 320 + c) = make_uint2(lo, hi);
}

// W (2,K,Cin) f32 -> Bt (Ctot, Kp) bf16 transposed, K..Kp zero padded
__global__ void convert_w(const float* __restrict__ W, u16* __restrict__ Bt,
                          int K, int Kp, int Cin, int Ctot) {
    int id = blockIdx.x * 256 + threadIdx.x;
    int j = id / Kp;
    int k = id - j * Kp;
    if (j >= Ctot) return;
    float v = 0.f;
    if (k < K) {
        int ord = (j >= Cin) ? 1 : 0;
        v = W[(size_t)ord * K * Cin + (size_t)k * Cin + (j & (Cin - 1))];
    }
    Bt[(size_t)j * Kp + k] = f2b(v);
}

// ---------- counting sort by dst ----------
__global__ void hist_kernel(const int* __restrict__ dst, int* __restrict__ cnt) {
    int e = blockIdx.x * 256 + threadIdx.x;
    if (e < EE) atomicAdd(&cnt[dst[e]], 1);
}

__global__ void scan_part(const int* __restrict__ cnt, int* __restrict__ psum) {
    int t = blockIdx.x * 256 + threadIdx.x;     // 8 blocks -> 2048 threads
    int b = t * CHUNK, e = min(b + CHUNK, NN);
    int s = 0;
    for (int i = b; i < e; ++i) s += cnt[i];
    psum[t] = s;
}

__global__ void scan_mid(int* psum) {           // 1 block, 256 threads, 2048 elems
    __shared__ int ts[256];
    int t = threadIdx.x;
    int v[8]; int s = 0;
    for (int j = 0; j < 8; ++j) { v[j] = psum[t * 8 + j]; s += v[j]; }
    ts[t] = s;
    __syncthreads();
    if (t == 0) { int run = 0; for (int i = 0; i < 256; ++i) { int x = ts[i]; ts[i] = run; run += x; } }
    __syncthreads();
    int run = ts[t];
    for (int j = 0; j < 8; ++j) { psum[t * 8 + j] = run; run += v[j]; }
}

__global__ void scan_fin(const int* __restrict__ cnt, const int* __restrict__ psum,
                         int* __restrict__ ns, int* __restrict__ cur) {
    int t = blockIdx.x * 256 + threadIdx.x;
    int b = t * CHUNK, e = min(b + CHUNK, NN);
    int run = psum[t];
    for (int i = b; i < e; ++i) { ns[i] = run; cur[i] = run; run += cnt[i]; }
    if (t == 0) ns[NN] = EE;
}

__global__ void scatter_kernel(const int* __restrict__ src, const int* __restrict__ dst,
                               const float* __restrict__ w, int* __restrict__ cur,
                               int2* __restrict__ se) {
    int e = blockIdx.x * 256 + threadIdx.x;
    if (e >= EE) return;
    int d = dst[e];
    int p = atomicAdd(&cur[d], 1);
    se[p] = make_int2(src[e], __float_as_int(w[e]));
}

// ---------- GEMM: C (bf16) = A (Mpad x K bf16) * Bt^T (Ctot x K bf16) ----------
// 128x128 tile, 4 waves each 64x64 (4x4 frags of 16x16x32 MFMA), BK=32.
__global__ __launch_bounds__(256) void gemm_bt(
    const u16* __restrict__ A, const u16* __restrict__ Bt,
    u16* __restrict__ out0, u16* __restrict__ out1,
    int K, int Ctot, int Mvalid)
{
    __shared__ __align__(16) u16 As[128 * 32];
    __shared__ __align__(16) u16 Bs[128 * 32];
    int tid = threadIdx.x;
    int nt = Ctot >> 7;
    int mtile = blockIdx.x / nt;
    int ntile = blockIdx.x - mtile * nt;
    int m0 = mtile << 7, n0 = ntile << 7;
    int w = tid >> 6, lane = tid & 63;
    int wm = (w >> 1) << 6, wn = (w & 1) << 6;
    int lr = lane & 15, lk = (lane >> 4) << 3;

    f32x4 acc[4][4] = {};

    for (int k0 = 0; k0 < K; k0 += 32) {
        // stage 128x32 A and B tiles: 512 chunks of 16B, 2 per thread each
#pragma unroll
        for (int t = 0; t < 2; ++t) {
            int cc = t * 256 + tid;
            int row = cc >> 2, sub = cc & 3;
            uint4 va = *(const uint4*)((const char*)A  + ((size_t)(m0 + row) * K + k0 + sub * 8) * 2);
            uint4 vb = *(const uint4*)((const char*)Bt + ((size_t)(n0 + row) * K + k0 + sub * 8) * 2);
            *(uint4*)((char*)As + (size_t)cc * 16) = va;
            *(uint4*)((char*)Bs + (size_t)cc * 16) = vb;
        }
        __syncthreads();
        bf16x8 af[4], bfr[4];
#pragma unroll
        for (int i = 0; i < 4; ++i) af[i]  = *(const bf16x8*)(&As[(wm + i * 16 + lr) * 32 + lk]);
#pragma unroll
        for (int j = 0; j < 4; ++j) bfr[j] = *(const bf16x8*)(&Bs[(wn + j * 16 + lr) * 32 + lk]);
#pragma unroll
        for (int i = 0; i < 4; ++i)
#pragma unroll
            for (int j = 0; j < 4; ++j)
                acc[i][j] = __builtin_amdgcn_mfma_f32_16x16x32_bf16(af[i], bfr[j], acc[i][j], 0, 0, 0);
        __syncthreads();
    }

    int Chalf = Ctot >> 1;
#pragma unroll
    for (int i = 0; i < 4; ++i) {
#pragma unroll
        for (int r = 0; r < 4; ++r) {
            int row = m0 + wm + i * 16 + ((lane >> 4) << 2) + r;
            if (row >= Mvalid) continue;
#pragma unroll
            for (int j = 0; j < 4; ++j) {
                int col = n0 + wn + j * 16 + lr;
                u16 v = f2b(acc[i][j][r]);
                if (col < Chalf) out0[(size_t)row * Chalf + col] = v;
                else             out1[(size_t)row * Chalf + (col - Chalf)] = v;
            }
        }
    }
}

// ---------- propagation layer 1: one wave per node, 256 cols ----------
__global__ __launch_bounds__(256) void prop1_kernel(
    const int2* __restrict__ se, const int* __restrict__ ns,
    const u16* __restrict__ xa, const u16* __restrict__ xb,
    const float* __restrict__ b1, u16* __restrict__ h1out)
{
    int gw = (blockIdx.x << 2) + (threadIdx.x >> 6);   // node id, < MPAD
    int lane = threadIdx.x & 63;
    u16* orow = h1out + (size_t)gw * 256 + lane * 4;
    if (gw >= NN) { *(uint2*)orow = make_uint2(0u, 0u); return; }

    int s = ns[gw], e = ns[gw + 1];
    float a0 = 0.f, a1 = 0.f, a2 = 0.f, a3 = 0.f;
    const u16* xbl = xb + lane * 4;
    for (int i = s; i < e; i += 4) {
        int2 q0 = se[i];
        int2 q1 = (i + 1 < e) ? se[i + 1] : make_int2(0, 0);
        int2 q2 = (i + 2 < e) ? se[i + 2] : make_int2(0, 0);
        int2 q3 = (i + 3 < e) ? se[i + 3] : make_int2(0, 0);
        uint2 v0 = *(const uint2*)(xbl + (size_t)q0.x * 256);
        uint2 v1 = *(const uint2*)(xbl + (size_t)q1.x * 256);
        uint2 v2 = *(const uint2*)(xbl + (size_t)q2.x * 256);
        uint2 v3 = *(const uint2*)(xbl + (size_t)q3.x * 256);
        float w0 = __int_as_float(q0.y), w1 = __int_as_float(q1.y);
        float w2 = __int_as_float(q2.y), w3 = __int_as_float(q3.y);
        a0 = fmaf(w0, bl(v0.x), a0); a1 = fmaf(w0, bh(v0.x), a1);
        a2 = fmaf(w0, bl(v0.y), a2); a3 = fmaf(w0, bh(v0.y), a3);
        a0 = fmaf(w1, bl(v1.x), a0); a1 = fmaf(w1, bh(v1.x), a1);
        a2 = fmaf(w1, bl(v1.y), a2); a3 = fmaf(w1, bh(v1.y), a3);
        a0 = fmaf(w2, bl(v2.x), a0); a1 = fmaf(w2, bh(v2.x), a1);
        a2 = fmaf(w2, bl(v2.y), a2); a3 = fmaf(w2, bh(v2.y), a3);
        a0 = fmaf(w3, bl(v3.x), a0); a1 = fmaf(w3, bh(v3.x), a1);
        a2 = fmaf(w3, bl(v3.y), a2); a3 = fmaf(w3, bh(v3.y), a3);
    }
    uint2 xv = *(const uint2*)(xa + (size_t)gw * 256 + lane * 4);
    float4 bv = *(const float4*)(b1 + lane * 4);
    float h0 = fmaxf(bl(xv.x) + a0 + bv.x, 0.f);
    float h1 = fmaxf(bh(xv.x) + a1 + bv.y, 0.f);
    float h2 = fmaxf(bl(xv.y) + a2 + bv.z, 0.f);
    float h3 = fmaxf(bh(xv.y) + a3 + bv.w, 0.f);
    uint2 ov;
    ov.x = (u32)f2b(h0) | ((u32)f2b(h1) << 16);
    ov.y = (u32)f2b(h2) | ((u32)f2b(h3) << 16);
    *(uint2*)orow = ov;
}

// ---------- propagation layer 2 + ReLU + global sum pool ----------
__global__ __launch_bounds__(256) void prop2_kernel(
    const int2* __restrict__ se, const int* __restrict__ ns,
    const u16* __restrict__ xa2, const u16* __restrict__ xb2,
    const float* __restrict__ b2, float* __restrict__ g)
{
    __shared__ float gpart[4][128];
    int w = threadIdx.x >> 6, lane = threadIdx.x & 63;
    int base = blockIdx.x * 32 + w * 8;
    float2 bv = *(const float2*)(b2 + lane * 2);
    float ga = 0.f, gb = 0.f;
    const u16* xb2l = xb2 + lane * 2;
    for (int t = 0; t < 8; ++t) {
        int n = base + t;
        if (n >= NN) break;
        int s = ns[n], e = ns[n + 1];
        float a0 = 0.f, a1 = 0.f;
        for (int i = s; i < e; i += 4) {
            int2 q0 = se[i];
            int2 q1 = (i + 1 < e) ? se[i + 1] : make_int2(0, 0);
            int2 q2 = (i + 2 < e) ? se[i + 2] : make_int2(0, 0);
            int2 q3 = (i + 3 < e) ? se[i + 3] : make_int2(0, 0);
            u32 v0 = *(const u32*)(xb2l + (size_t)q0.x * 128);
            u32 v1 = *(const u32*)(xb2l + (size_t)q1.x * 128);
            u32 v2 = *(const u32*)(xb2l + (size_t)q2.x * 128);
            u32 v3 = *(const u32*)(xb2l + (size_t)q3.x * 128);
            float w0 = __int_as_float(q0.y), w1 = __int_as_float(q1.y);
            float w2 = __int_as_float(q2.y), w3 = __int_as_float(q3.y);
            a0 = fmaf(w0, bl(v0), a0); a1 = fmaf(w0, bh(v0), a1);
            a0 = fmaf(w1, bl(v1), a0); a1 = fmaf(w1, bh(v1), a1);
            a0 = fmaf(w2, bl(v2), a0); a1 = fmaf(w2, bh(v2), a1);
            a0 = fmaf(w3, bl(v3), a0); a1 = fmaf(w3, bh(v3), a1);
        }
        u32 xv = *(const u32*)(xa2 + (size_t)n * 128 + lane * 2);
        ga += fmaxf(bl(xv) + a0 + bv.x, 0.f);
        gb += fmaxf(bh(xv) + a1 + bv.y, 0.f);
    }
    gpart[w][lane * 2]     = ga;
    gpart[w][lane * 2 + 1] = gb;
    __syncthreads();
    if (threadIdx.x < 128) {
        float s = gpart[0][threadIdx.x] + gpart[1][threadIdx.x] +
                  gpart[2][threadIdx.x] + gpart[3][threadIdx.x];
        atomicAdd(&g[threadIdx.x], s);
    }
}

// ---------- MLP head + softmax ----------
__global__ void head_kernel(const float* __restrict__ g,
                            const float* __restrict__ Wd1, const float* __restrict__ bd1,
                            const float* __restrict__ Wd2, const float* __restrict__ bd2,
                            float* __restrict__ out)
{
    __shared__ float gs[128], ds[64], ls[20];
    int t = threadIdx.x;
    if (t < 128) gs[t] = g[t];
    __syncthreads();
    if (t < 64) {
        float a = bd1[t];
        for (int i = 0; i < 128; ++i) a = fmaf(gs[i], Wd1[i * 64 + t], a);
        ds[t] = fmaxf(a, 0.f);
    }
    __syncthreads();
    if (t < 20) {
        float a = bd2[t];
        for (int i = 0; i < 64; ++i) a = fmaf(ds[i], Wd2[i * 20 + t], a);
        ls[t] = a;
    }
    __syncthreads();
    if (t == 0) {
        float m = ls[0];
        for (int i = 1; i < 20; ++i) m = fmaxf(m, ls[i]);
        float s = 0.f; float e[20];
        for (int i = 0; i < 20; ++i) { e[i] = expf(ls[i] - m); s += e[i]; }
        float inv = 1.f / s;
        for (int i = 0; i < 20; ++i) out[i] = e[i] * inv;
    }
}

// ---------- launcher ----------
extern "C" void kernel_launch(void* const* d_in, const int* in_sizes, int n_in,
                              void* d_out, int out_size, void* d_ws, size_t ws_size,
                              hipStream_t stream)
{
    const float* x   = (const float*)d_in[0];
    const int*   esrc= (const int*)d_in[1];
    const int*   edst= (const int*)d_in[2];
    const float* ew  = (const float*)d_in[3];
    const float* W1  = (const float*)d_in[4];
    const float* b1  = (const float*)d_in[5];
    const float* W2  = (const float*)d_in[6];
    const float* b2  = (const float*)d_in[7];
    const float* Wd1 = (const float*)d_in[8];
    const float* bd1 = (const float*)d_in[9];
    const float* Wd2 = (const float*)d_in[10];
    const float* bd2 = (const float*)d_in[11];
    float* out = (float*)d_out;

    char* ws = (char*)d_ws;
    size_t off = 0;
    auto take = [&](size_t b) { off = (off + 255) & ~(size_t)255; size_t o = off; off += b; return o; };
    size_t o_xbf = take((size_t)MPAD * 320 * 2);   // 128.0 MB; later reused as h1 (MPAD*256*2)
    size_t o_xa  = take((size_t)NN * 256 * 2);     // 102.4 MB; later reused as xa2|xb2
    size_t o_xb  = take((size_t)NN * 256 * 2);     // 102.4 MB
    size_t o_bt1 = take((size_t)512 * 320 * 2);
    size_t o_bt2 = take((size_t)256 * 256 * 2);
    size_t o_se  = take((size_t)EE * 8);           // 51.2 MB
    size_t o_cnt = take((size_t)NN * 4);
    size_t o_ns  = take((size_t)(NN + 1) * 4);
    size_t o_cur = take((size_t)NN * 4);
    size_t o_ps  = take((size_t)SCAN_T * 4);
    size_t o_g   = take((size_t)128 * 4);

    u16*  xbf = (u16*)(ws + o_xbf);
    u16*  h1  = (u16*)(ws + o_xbf);                 // alias: xbf dead after gemm1
    u16*  xa  = (u16*)(ws + o_xa);
    u16*  xa2 = (u16*)(ws + o_xa);                  // alias: xa dead after prop1
    u16*  xb2 = (u16*)(ws + o_xa + (size_t)NN * 128 * 2);
    u16*  xb  = (u16*)(ws + o_xb);
    u16*  bt1 = (u16*)(ws + o_bt1);
    u16*  bt2 = (u16*)(ws + o_bt2);
    int2* se  = (int2*)(ws + o_se);
    int*  cnt = (int*)(ws + o_cnt);
    int*  ns  = (int*)(ws + o_ns);
    int*  cur = (int*)(ws + o_cur);
    int*  ps  = (int*)(ws + o_ps);
    float* g  = (float*)(ws + o_g);

    zero_kernel<<<(NN + 255) / 256, 256, 0, stream>>>(cnt, g, NN);
    convert_x<<<(MPAD * 80) / 256, 256, 0, stream>>>(x, xbf);
    convert_w<<<(512 * 320) / 256, 256, 0, stream>>>(W1, bt1, 300, 320, 256, 512);
    convert_w<<<(256 * 256) / 256, 256, 0, stream>>>(W2, bt2, 256, 256, 128, 256);

    hist_kernel<<<EE / 256, 256, 0, stream>>>(edst, cnt);
    scan_part<<<SCAN_T / 256, 256, 0, stream>>>(cnt, ps);
    scan_mid<<<1, 256, 0, stream>>>(ps);
    scan_fin<<<SCAN_T / 256, 256, 0, stream>>>(cnt, ps, ns, cur);
    scatter_kernel<<<EE / 256, 256, 0, stream>>>(esrc, edst, ew, cur, se);

    // layer 1: [xa | xb] = xbf @ [W1[0] | W1[1]]
    gemm_bt<<<(MPAD / 128) * 4, 256, 0, stream>>>(xbf, bt1, xa, xb, 320, 512, NN);
    prop1_kernel<<<MPAD / 4, 256, 0, stream>>>(se, ns, xa, xb, b1, h1);
    // layer 2: [xa2 | xb2] = h1 @ [W2[0] | W2[1]]
    gemm_bt<<<(MPAD / 128) * 2, 256, 0, stream>>>(h1, bt2, xa2, xb2, 256, 256, NN);
    prop2_kernel<<<NN / 32, 256, 0, stream>>>(se, ns, xa2, xb2, b2, g);

    head_kernel<<<1, 128, 0, stream>>>(g, Wd1, bd1, Wd2, bd2, out);
}